// Round 3
// baseline (142.451 us; speedup 1.0000x reference)
//
#include <hip/hip_runtime.h>
#include <math.h>

#define B_    32
#define CIN   16
#define T_    2048
#define TP4   514    // float4 per padded row: 1 front + 512 + 1 back
#define NE    8
#define NG    8
#define CPG   16
#define HID   128
#define KW    5
#define EPS_  1e-5f

__device__ __forceinline__ float gelu_f(float y) {
    return 0.5f * y * (1.0f + erff(y * 0.70710678118654752440f));
}

// XOR swizzle on within-row float4 index (involution; write AND read side).
__device__ __forceinline__ int swz(int i4) { return i4 ^ ((i4 >> 3) & 7); }

// ---------------------------------------------------------------------------
// K1: router conv (no bias) -> GroupNorm -> GELU -> mean over T  => r0 (B,128)
// block = (b, g), 512 threads (8 waves, 2/SIMD, VGPR cap 256 -> no spill)
// thread tile: 4 co x 16 t
// ---------------------------------------------------------------------------
__global__ __launch_bounds__(512, 2) void router_conv_kernel(
    const float* __restrict__ x, const float* __restrict__ rw,
    const float* __restrict__ rg, const float* __restrict__ rb,
    float* __restrict__ r0)
{
    __shared__ float4 xs4[CIN * TP4];
    __shared__ float wl[CPG * 128];        // [co][ci*8+k], k padded 5->8
    __shared__ float red[8], redq[8];
    __shared__ float rsum[2][CPG];

    const int b = blockIdx.x, g = blockIdx.y;
    const int tid = threadIdx.x;
    const int lane = tid & 63, wv = tid >> 6;
    const int coq = wv & 3, tblk = wv >> 2;          // 4 co-quads x 2 t-halves

    // ---- stage x[b] (16 x 2048) into swizzled LDS
    const float4* xsrc = (const float4*)(x + (size_t)b * CIN * T_);
    for (int i = tid; i < CIN * T_ / 4; i += 512) {
        int row = i >> 9, c4 = i & 511;
        xs4[row * TP4 + swz(c4 + 1)] = xsrc[i];
    }
    if (tid < 32) {           // zero pads: i4 = 0 and 513 (swz fixed points)
        int row = tid >> 1;
        float4 z = {0.f, 0.f, 0.f, 0.f};
        xs4[row * TP4 + ((tid & 1) ? 513 : 0)] = z;
    }
    // ---- stage weights for this group's 16 out-channels
    const float* wsrc = rw + (size_t)g * CPG * CIN * KW;
    for (int i = tid; i < CPG * CIN * KW; i += 512) {
        int co = i / 80, rem = i - co * 80;
        int ci = rem / 5, k = rem - ci * 5;
        wl[co * 128 + ci * 8 + k] = wsrc[i];
    }
    __syncthreads();

    // ---- conv: each thread 4 co x 16 t
    float c[64];
    #pragma unroll
    for (int i = 0; i < 64; ++i) c[i] = 0.0f;

    const int i4base = tblk * 256 + lane * 4;   // padded float4 idx of t0-4
    for (int ci = 0; ci < CIN; ++ci) {
        float xw[24];
        const float4* xrow = &xs4[ci * TP4];
        #pragma unroll
        for (int j = 0; j < 6; ++j)
            *(float4*)&xw[4 * j] = xrow[swz(i4base + j)];
        #pragma unroll
        for (int cc = 0; cc < 4; ++cc) {
            const float* wp = &wl[(coq * 4 + cc) * 128 + ci * 8];
            float4 wa = *(const float4*)wp;
            float w4 = wp[4];
            #pragma unroll
            for (int tt = 0; tt < 16; ++tt) {
                c[cc * 16 + tt] += wa.x * xw[tt + 2] + wa.y * xw[tt + 3] +
                                   wa.z * xw[tt + 4] + wa.w * xw[tt + 5] +
                                   w4   * xw[tt + 6];
            }
        }
    }

    // ---- GroupNorm stats
    float s = 0.f, sq = 0.f;
    #pragma unroll
    for (int i = 0; i < 64; ++i) { s += c[i]; sq += c[i] * c[i]; }
    for (int d = 1; d < 64; d <<= 1) {
        s  += __shfl_xor(s, d);
        sq += __shfl_xor(sq, d);
    }
    if (lane == 0) { red[wv] = s; redq[wv] = sq; }
    __syncthreads();
    float S = 0.f, SQ = 0.f;
    for (int i = 0; i < 8; ++i) { S += red[i]; SQ += redq[i]; }
    const float inv_n = 1.0f / (CPG * T_);
    float mu = S * inv_n;
    float var = SQ * inv_n - mu * mu;
    float rstd = rsqrtf(var + EPS_);

    // ---- normalize, GELU, temporal partial sums
    float ts[4];
    #pragma unroll
    for (int cc = 0; cc < 4; ++cc) {
        float ga = rg[g * CPG + coq * 4 + cc];
        float be = rb[g * CPG + coq * 4 + cc];
        float t = 0.f;
        #pragma unroll
        for (int tt = 0; tt < 16; ++tt) {
            float y = (c[cc * 16 + tt] - mu) * rstd * ga + be;
            t += gelu_f(y);
        }
        ts[cc] = t;
    }
    for (int d = 1; d < 64; d <<= 1) {
        #pragma unroll
        for (int cc = 0; cc < 4; ++cc) ts[cc] += __shfl_xor(ts[cc], d);
    }
    if (lane == 0) {
        #pragma unroll
        for (int cc = 0; cc < 4; ++cc) rsum[tblk][coq * 4 + cc] = ts[cc];
    }
    __syncthreads();
    if (tid < CPG) {
        float a = rsum[0][tid] + rsum[1][tid];
        r0[b * HID + g * CPG + tid] = a * (1.0f / T_);
    }
}

// ---------------------------------------------------------------------------
// K2: router MLP + demo embedder + gate + softmax + top-2  (block per b)
// ---------------------------------------------------------------------------
__global__ void router_gate_kernel(
    const float* __restrict__ r0, const float* __restrict__ demo,
    const float* __restrict__ m1w, const float* __restrict__ m1b,
    const float* __restrict__ lng, const float* __restrict__ lnb,
    const float* __restrict__ m2w, const float* __restrict__ m2b,
    const float* __restrict__ d1w, const float* __restrict__ d1b,
    const float* __restrict__ dlng, const float* __restrict__ dlnb,
    const float* __restrict__ d2w, const float* __restrict__ d2b,
    const float* __restrict__ gw, const float* __restrict__ gb,
    float* __restrict__ gateW, int* __restrict__ gateI)
{
    __shared__ float sh[128];
    __shared__ float dd[32];
    __shared__ float rr[80];
    __shared__ float glds[8];
    __shared__ float red[2], redq[2];

    const int b = blockIdx.x;
    const int j = threadIdx.x;
    const int lane = j & 63, wv = j >> 6;

    sh[j] = r0[b * HID + j];
    __syncthreads();

    float v = m1b[j];
    for (int i = 0; i < 128; ++i) v += sh[i] * m1w[j * 128 + i];
    float s = v, sq = v * v;
    for (int d = 1; d < 64; d <<= 1) { s += __shfl_xor(s, d); sq += __shfl_xor(sq, d); }
    if (lane == 0) { red[wv] = s; redq[wv] = sq; }
    __syncthreads();
    float S = red[0] + red[1], SQ = redq[0] + redq[1];
    float mu = S * (1.f / 128.f), var = SQ * (1.f / 128.f) - mu * mu;
    float h = (v - mu) * rsqrtf(var + EPS_) * lng[j] + lnb[j];
    float gv = gelu_f(h);
    __syncthreads();
    sh[j] = gv;
    __syncthreads();

    if (j < 64) {
        float rv = m2b[j];
        for (int i = 0; i < 128; ++i) rv += sh[i] * m2w[j * 128 + i];
        rr[j] = rv;
    } else if (j < 96) {
        int jd = j - 64;
        float u = d1b[jd];
        for (int i = 0; i < 8; ++i) u += demo[b * 8 + i] * d1w[jd * 8 + i];
        float s2 = u, q2 = u * u;
        for (int d = 1; d < 32; d <<= 1) { s2 += __shfl_xor(s2, d, 32); q2 += __shfl_xor(q2, d, 32); }
        float mu2 = s2 * (1.f / 32.f), var2 = q2 * (1.f / 32.f) - mu2 * mu2;
        float y = (u - mu2) * rsqrtf(var2 + EPS_) * dlng[jd] + dlnb[jd];
        dd[jd] = gelu_f(y);
    }
    __syncthreads();
    if (j < 16) {
        float rv = d2b[j];
        for (int i = 0; i < 32; ++i) rv += dd[i] * d2w[j * 32 + i];
        rr[64 + j] = rv;
    }
    __syncthreads();
    if (j < 8) {
        float lg = gb[j];
        for (int i = 0; i < 80; ++i) lg += rr[i] * gw[j * 80 + i];
        glds[j] = lg;
    }
    __syncthreads();
    if (j == 0) {
        float wsf[8];
        float m = glds[0];
        for (int e = 1; e < 8; ++e) m = fmaxf(m, glds[e]);
        float ssum = 0.f;
        for (int e = 0; e < 8; ++e) { wsf[e] = expf(glds[e] - m); ssum += wsf[e]; }
        for (int e = 0; e < 8; ++e) wsf[e] /= ssum;
        int i1 = 0;
        for (int e = 1; e < 8; ++e) if (wsf[e] > wsf[i1]) i1 = e;
        int i2 = (i1 == 0) ? 1 : 0;
        for (int e = 0; e < 8; ++e) if (e != i1 && wsf[e] > wsf[i2]) i2 = e;
        float a = wsf[i1], b2 = wsf[i2];
        float dn = a + b2 + 1e-9f;
        gateW[b * 2 + 0] = a / dn;
        gateW[b * 2 + 1] = b2 / dn;
        gateI[b * 2 + 0] = i1;
        gateI[b * 2 + 1] = i2;
    }
}

// ---------------------------------------------------------------------------
// K3: shared + top-2 expert convs -> GN -> GELU -> weighted sum -> out
// block = (b, g), 512 threads (8 waves, VGPR cap 256 -> no spill)
// thread tile: 4 co x 16 t; all 3 slots' weights preloaded
// ---------------------------------------------------------------------------
__global__ __launch_bounds__(512, 2) void experts_kernel(
    const float* __restrict__ x,
    const float* __restrict__ ew, const float* __restrict__ eb,
    const float* __restrict__ eg, const float* __restrict__ ebt,
    const float* __restrict__ sw, const float* __restrict__ sb,
    const float* __restrict__ sg, const float* __restrict__ sbt,
    const float* __restrict__ gateW, const int* __restrict__ gateI,
    float* __restrict__ out)
{
    __shared__ float4 xs4[CIN * TP4];
    __shared__ float wl[3][CPG * 128];
    __shared__ float bl[3][CPG], gml[3][CPG], btl[3][CPG];
    __shared__ float red[3][8], redq[3][8];

    const int b = blockIdx.x, g = blockIdx.y;
    const int tid = threadIdx.x;
    const int lane = tid & 63, wv = tid >> 6;
    const int coq = wv & 3, tblk = wv >> 2;

    const int e1 = gateI[b * 2 + 0], e2 = gateI[b * 2 + 1];
    const float scl[3] = {1.0f, gateW[b * 2 + 0], gateW[b * 2 + 1]};

    // ---- stage x[b] (swizzled)
    const float4* xsrc = (const float4*)(x + (size_t)b * CIN * T_);
    for (int i = tid; i < CIN * T_ / 4; i += 512) {
        int row = i >> 9, c4 = i & 511;
        xs4[row * TP4 + swz(c4 + 1)] = xsrc[i];
    }
    if (tid < 32) {
        int row = tid >> 1;
        float4 z = {0.f, 0.f, 0.f, 0.f};
        xs4[row * TP4 + ((tid & 1) ? 513 : 0)] = z;
    }

    // ---- stage ALL 3 slots' weights + params up front
    const float* wbase[3] = {
        sw + (size_t)g * CPG * CIN * KW,
        ew + ((size_t)e1 * 128 + g * CPG) * CIN * KW,
        ew + ((size_t)e2 * 128 + g * CPG) * CIN * KW };
    for (int i = tid; i < 3 * CPG * CIN * KW; i += 512) {
        int slot = i / 1280, j = i - slot * 1280;
        int co = j / 80, rem = j - co * 80;
        int ci = rem / 5, k = rem - ci * 5;
        wl[slot][co * 128 + ci * 8 + k] = wbase[slot][j];
    }
    if (tid < 48) {
        int slot = tid >> 4, cc = tid & 15;
        const float *bs, *gs, *bt;
        if (slot == 0) { bs = sb; gs = sg; bt = sbt; }
        else {
            int e = (slot == 1) ? e1 : e2;
            bs = eb + e * 128; gs = eg + e * 128; bt = ebt + e * 128;
        }
        bl[slot][cc]  = bs[g * CPG + cc];
        gml[slot][cc] = gs[g * CPG + cc];
        btl[slot][cc] = bt[g * CPG + cc];
    }
    __syncthreads();

    float acc[64];
    #pragma unroll
    for (int i = 0; i < 64; ++i) acc[i] = 0.0f;

    const int i4base = tblk * 256 + lane * 4;

    for (int slot = 0; slot < 3; ++slot) {
        // ---- conv (+bias)
        float c[64];
        #pragma unroll
        for (int cc = 0; cc < 4; ++cc) {
            float bb = bl[slot][coq * 4 + cc];
            #pragma unroll
            for (int tt = 0; tt < 16; ++tt) c[cc * 16 + tt] = bb;
        }
        for (int ci = 0; ci < CIN; ++ci) {
            float xw[24];
            const float4* xrow = &xs4[ci * TP4];
            #pragma unroll
            for (int j = 0; j < 6; ++j)
                *(float4*)&xw[4 * j] = xrow[swz(i4base + j)];
            #pragma unroll
            for (int cc = 0; cc < 4; ++cc) {
                const float* wp = &wl[slot][(coq * 4 + cc) * 128 + ci * 8];
                float4 wa = *(const float4*)wp;
                float w4 = wp[4];
                #pragma unroll
                for (int tt = 0; tt < 16; ++tt) {
                    c[cc * 16 + tt] += wa.x * xw[tt + 2] + wa.y * xw[tt + 3] +
                                       wa.z * xw[tt + 4] + wa.w * xw[tt + 5] +
                                       w4   * xw[tt + 6];
                }
            }
        }

        // ---- GN stats (per-slot buffers -> single barrier per slot)
        float s = 0.f, sq = 0.f;
        #pragma unroll
        for (int i = 0; i < 64; ++i) { s += c[i]; sq += c[i] * c[i]; }
        for (int d = 1; d < 64; d <<= 1) {
            s  += __shfl_xor(s, d);
            sq += __shfl_xor(sq, d);
        }
        if (lane == 0) { red[slot][wv] = s; redq[slot][wv] = sq; }
        __syncthreads();
        float S = 0.f, SQ = 0.f;
        for (int i = 0; i < 8; ++i) { S += red[slot][i]; SQ += redq[slot][i]; }
        const float inv_n = 1.0f / (CPG * T_);
        float mu = S * inv_n;
        float var = SQ * inv_n - mu * mu;
        float rstd = rsqrtf(var + EPS_);

        // ---- normalize + GELU + weighted accumulate
        float scale = scl[slot];
        #pragma unroll
        for (int cc = 0; cc < 4; ++cc) {
            float ga = gml[slot][coq * 4 + cc];
            float be = btl[slot][coq * 4 + cc];
            #pragma unroll
            for (int tt = 0; tt < 16; ++tt) {
                float y = (c[cc * 16 + tt] - mu) * rstd * ga + be;
                acc[cc * 16 + tt] += scale * gelu_f(y);
            }
        }
    }

    // ---- store (per lane: 64B contiguous per cc)
    const int t0 = tblk * 1024 + lane * 16;
    #pragma unroll
    for (int cc = 0; cc < 4; ++cc) {
        int co = g * CPG + coq * 4 + cc;
        float* op = out + ((size_t)(b * 128 + co)) * T_ + t0;
        #pragma unroll
        for (int q = 0; q < 4; ++q) {
            float4 o = { acc[cc * 16 + q * 4 + 0], acc[cc * 16 + q * 4 + 1],
                         acc[cc * 16 + q * 4 + 2], acc[cc * 16 + q * 4 + 3] };
            *(float4*)(op + q * 4) = o;
        }
    }
}

// ---------------------------------------------------------------------------
extern "C" void kernel_launch(void* const* d_in, const int* in_sizes, int n_in,
                              void* d_out, int out_size, void* d_ws, size_t ws_size,
                              hipStream_t stream)
{
    const float* x    = (const float*)d_in[0];
    const float* demo = (const float*)d_in[1];
    const float* rw   = (const float*)d_in[2];
    const float* rg   = (const float*)d_in[3];
    const float* rb   = (const float*)d_in[4];
    const float* m1w  = (const float*)d_in[5];
    const float* m1b  = (const float*)d_in[6];
    const float* lng  = (const float*)d_in[7];
    const float* lnb  = (const float*)d_in[8];
    const float* m2w  = (const float*)d_in[9];
    const float* m2b  = (const float*)d_in[10];
    const float* d1w  = (const float*)d_in[11];
    const float* d1b  = (const float*)d_in[12];
    const float* dlng = (const float*)d_in[13];
    const float* dlnb = (const float*)d_in[14];
    const float* d2w  = (const float*)d_in[15];
    const float* d2b  = (const float*)d_in[16];
    const float* gw   = (const float*)d_in[17];
    const float* gb   = (const float*)d_in[18];
    const float* ew   = (const float*)d_in[19];
    const float* eb   = (const float*)d_in[20];
    const float* eg   = (const float*)d_in[21];
    const float* ebt  = (const float*)d_in[22];
    const float* sw   = (const float*)d_in[23];
    const float* sb   = (const float*)d_in[24];
    const float* sg   = (const float*)d_in[25];
    const float* sbt  = (const float*)d_in[26];
    float* out = (float*)d_out;

    float* r0    = (float*)d_ws;
    float* gateW = r0 + B_ * HID;
    int*   gateI = (int*)(gateW + 64);

    dim3 gridc(B_, NG);   // b fastest -> all 8 g-blocks of one b share an XCD
    router_conv_kernel<<<gridc, 512, 0, stream>>>(x, rw, rg, rb, r0);
    router_gate_kernel<<<dim3(B_), 128, 0, stream>>>(
        r0, demo, m1w, m1b, lng, lnb, m2w, m2b,
        d1w, d1b, dlng, dlnb, d2w, d2b, gw, gb, gateW, gateI);
    experts_kernel<<<gridc, 512, 0, stream>>>(
        x, ew, eb, eg, ebt, sw, sb, sg, sbt, gateW, gateI, out);
    (void)in_sizes; (void)n_in; (void)out_size; (void)ws_size;
}

// Round 4
// 86.563 us; speedup vs baseline: 1.6456x; 1.6456x over previous
//
#include <hip/hip_runtime.h>
#include <math.h>

#define B_    32
#define CIN   16
#define T_    2048
#define NE    8
#define NG    8
#define CPG   16
#define HID   128
#define KW    5
#define EPS_  1e-5f

#define ROWB  24      // bf16 elems per xT row (16 used + pad) -> 48B rows
#define NROW  2053    // rows t' = t+2, t in [-2, 2050]
#define NTH   512

typedef float f32x4 __attribute__((ext_vector_type(4)));
typedef short s16x8 __attribute__((ext_vector_type(8)));

__device__ __forceinline__ float gelu_f(float y) {
    return 0.5f * y * (1.0f + erff(y * 0.70710678118654752440f));
}

__device__ __forceinline__ short bf16r(float f) {
    unsigned u = __builtin_bit_cast(unsigned, f);
    u = u + 0x7FFFu + ((u >> 16) & 1u);   // round-to-nearest-even
    return (short)(u >> 16);
}

// ---------------------------------------------------------------------------
// K1: router conv (no bias) -> GroupNorm -> GELU -> mean over T => r0 (B,128)
// block=(b,g), 512 thr. MFMA 16x16x32 bf16, single conv pass (c kept in regs)
// ---------------------------------------------------------------------------
__global__ __launch_bounds__(512, 2) void router_conv_kernel(
    const float* __restrict__ x, const float* __restrict__ rw,
    const float* __restrict__ rg, const float* __restrict__ rb,
    float* __restrict__ r0)
{
    __shared__ short xs[NROW * ROWB];
    __shared__ float redS[8], redQ[8];
    __shared__ float rsum[8][CPG];

    const int b = blockIdx.x, g = blockIdx.y;
    const int tid = threadIdx.x;
    const int l = tid & 63, wv = tid >> 6;
    const int n = l & 15, grp = l >> 4;
    const int s_ = grp >> 1, cib = (grp & 1) * 8;

    // ---- stage x[b] -> bf16 transposed xT[t+2][ci]
    const float* xb = x + (size_t)b * CIN * T_;
    for (int i = tid; i < CIN * T_; i += NTH) {
        int ci = i >> 11, t = i & 2047;
        xs[(t + 2) * ROWB + ci] = bf16r(xb[i]);
    }
    for (int i = tid; i < 5 * ROWB; i += NTH) {
        int r = i / ROWB, cc = i - r * ROWB;
        int row = (r < 2) ? r : 2048 + r;   // rows -2,-1, 2048..2050
        xs[row * ROWB + cc] = 0;
    }

    // ---- A fragments (weights, bf16) : lane holds W[co=l&15][cib+j][sh]
    s16x8 afr[3];
    #pragma unroll
    for (int p = 0; p < 3; ++p) {
        int sh = 2 * p + s_;
        s16x8 a;
        if (sh < 5) {
            const float* wp = rw + ((size_t)(g * CPG + n)) * (CIN * KW) + cib * KW + sh;
            #pragma unroll
            for (int j = 0; j < 8; ++j) a[j] = bf16r(wp[j * KW]);
        } else {
            #pragma unroll
            for (int j = 0; j < 8; ++j) a[j] = 0;
        }
        afr[p] = a;
    }
    // per-co (C/D row) gamma/beta: co_d = grp*4 + r
    float ga[4], be[4];
    #pragma unroll
    for (int r = 0; r < 4; ++r) {
        int co = g * CPG + grp * 4 + r;
        ga[r] = rg[co]; be[r] = rb[co];
    }
    __syncthreads();

    // ---- conv: 16 t-tiles per wave, keep results in regs
    f32x4 cst[16];
    float sA = 0.f, qA = 0.f;
    #pragma unroll
    for (int tile = 0; tile < 16; ++tile) {
        const int t0 = (wv * 16 + tile) * 16;
        s16x8 bf0 = *(const s16x8*)&xs[(t0 + n + 0 + s_) * ROWB + cib];
        s16x8 bf1 = *(const s16x8*)&xs[(t0 + n + 2 + s_) * ROWB + cib];
        s16x8 bf2 = *(const s16x8*)&xs[(t0 + n + 4 + s_) * ROWB + cib];
        f32x4 c = {0.f, 0.f, 0.f, 0.f};
        c = __builtin_amdgcn_mfma_f32_16x16x32_bf16(afr[0], bf0, c, 0, 0, 0);
        c = __builtin_amdgcn_mfma_f32_16x16x32_bf16(afr[1], bf1, c, 0, 0, 0);
        c = __builtin_amdgcn_mfma_f32_16x16x32_bf16(afr[2], bf2, c, 0, 0, 0);
        cst[tile] = c;
        #pragma unroll
        for (int r = 0; r < 4; ++r) { sA += c[r]; qA += c[r] * c[r]; }
    }

    // ---- GN stats
    for (int d = 1; d < 64; d <<= 1) {
        sA += __shfl_xor(sA, d);
        qA += __shfl_xor(qA, d);
    }
    if (l == 0) { redS[wv] = sA; redQ[wv] = qA; }
    __syncthreads();
    float S = 0.f, Q = 0.f;
    for (int i = 0; i < 8; ++i) { S += redS[i]; Q += redQ[i]; }
    const float inv_n = 1.0f / (CPG * T_);
    float mu = S * inv_n;
    float rs = rsqrtf(Q * inv_n - mu * mu + EPS_);

    // ---- normalize + GELU + temporal partial sums
    f32x4 tacc = {0.f, 0.f, 0.f, 0.f};
    #pragma unroll
    for (int tile = 0; tile < 16; ++tile) {
        #pragma unroll
        for (int r = 0; r < 4; ++r) {
            float y = (cst[tile][r] - mu) * rs * ga[r] + be[r];
            tacc[r] += gelu_f(y);
        }
    }
    #pragma unroll
    for (int r = 0; r < 4; ++r)
        for (int d = 1; d < 16; d <<= 1)
            tacc[r] += __shfl_xor(tacc[r], d);
    if (n == 0) {
        #pragma unroll
        for (int r = 0; r < 4; ++r) rsum[wv][grp * 4 + r] = tacc[r];
    }
    __syncthreads();
    if (tid < CPG) {
        float a = 0.f;
        for (int w = 0; w < 8; ++w) a += rsum[w][tid];
        r0[b * HID + g * CPG + tid] = a * (1.0f / T_);
    }
}

// ---------------------------------------------------------------------------
// K2: router MLP + demo embedder + gate + softmax + top-2  (block per b)
// ---------------------------------------------------------------------------
__global__ void router_gate_kernel(
    const float* __restrict__ r0, const float* __restrict__ demo,
    const float* __restrict__ m1w, const float* __restrict__ m1b,
    const float* __restrict__ lng, const float* __restrict__ lnb,
    const float* __restrict__ m2w, const float* __restrict__ m2b,
    const float* __restrict__ d1w, const float* __restrict__ d1b,
    const float* __restrict__ dlng, const float* __restrict__ dlnb,
    const float* __restrict__ d2w, const float* __restrict__ d2b,
    const float* __restrict__ gw, const float* __restrict__ gb,
    float* __restrict__ gateW, int* __restrict__ gateI)
{
    __shared__ float sh[128];
    __shared__ float dd[32];
    __shared__ float rr[80];
    __shared__ float glds[8];
    __shared__ float red[2], redq[2];

    const int b = blockIdx.x;
    const int j = threadIdx.x;
    const int lane = j & 63, wv = j >> 6;

    sh[j] = r0[b * HID + j];
    __syncthreads();

    float v = m1b[j];
    for (int i = 0; i < 128; ++i) v += sh[i] * m1w[j * 128 + i];
    float s = v, sq = v * v;
    for (int d = 1; d < 64; d <<= 1) { s += __shfl_xor(s, d); sq += __shfl_xor(sq, d); }
    if (lane == 0) { red[wv] = s; redq[wv] = sq; }
    __syncthreads();
    float S = red[0] + red[1], SQ = redq[0] + redq[1];
    float mu = S * (1.f / 128.f), var = SQ * (1.f / 128.f) - mu * mu;
    float h = (v - mu) * rsqrtf(var + EPS_) * lng[j] + lnb[j];
    float gv = gelu_f(h);
    __syncthreads();
    sh[j] = gv;
    __syncthreads();

    if (j < 64) {
        float rv = m2b[j];
        for (int i = 0; i < 128; ++i) rv += sh[i] * m2w[j * 128 + i];
        rr[j] = rv;
    } else if (j < 96) {
        int jd = j - 64;
        float u = d1b[jd];
        for (int i = 0; i < 8; ++i) u += demo[b * 8 + i] * d1w[jd * 8 + i];
        float s2 = u, q2 = u * u;
        for (int d = 1; d < 32; d <<= 1) { s2 += __shfl_xor(s2, d, 32); q2 += __shfl_xor(q2, d, 32); }
        float mu2 = s2 * (1.f / 32.f), var2 = q2 * (1.f / 32.f) - mu2 * mu2;
        float y = (u - mu2) * rsqrtf(var2 + EPS_) * dlng[jd] + dlnb[jd];
        dd[jd] = gelu_f(y);
    }
    __syncthreads();
    if (j < 16) {
        float rv = d2b[j];
        for (int i = 0; i < 32; ++i) rv += dd[i] * d2w[j * 32 + i];
        rr[64 + j] = rv;
    }
    __syncthreads();
    if (j < 8) {
        float lg = gb[j];
        for (int i = 0; i < 80; ++i) lg += rr[i] * gw[j * 80 + i];
        glds[j] = lg;
    }
    __syncthreads();
    if (j == 0) {
        float wsf[8];
        float m = glds[0];
        for (int e = 1; e < 8; ++e) m = fmaxf(m, glds[e]);
        float ssum = 0.f;
        for (int e = 0; e < 8; ++e) { wsf[e] = expf(glds[e] - m); ssum += wsf[e]; }
        for (int e = 0; e < 8; ++e) wsf[e] /= ssum;
        int i1 = 0;
        for (int e = 1; e < 8; ++e) if (wsf[e] > wsf[i1]) i1 = e;
        int i2 = (i1 == 0) ? 1 : 0;
        for (int e = 0; e < 8; ++e) if (e != i1 && wsf[e] > wsf[i2]) i2 = e;
        float a = wsf[i1], b2 = wsf[i2];
        float dn = a + b2 + 1e-9f;
        gateW[b * 2 + 0] = a / dn;
        gateW[b * 2 + 1] = b2 / dn;
        gateI[b * 2 + 0] = i1;
        gateI[b * 2 + 1] = i2;
    }
}

// ---------------------------------------------------------------------------
// K3: shared + top-2 experts: conv -> GN -> GELU -> weighted sum -> out
// block=(b,g), 512 thr. MFMA; pass1 stats (recompute), pass2 epilogue+store.
// B-fragments shared across the 3 slots.
// ---------------------------------------------------------------------------
__global__ __launch_bounds__(512, 2) void experts_kernel(
    const float* __restrict__ x,
    const float* __restrict__ ew, const float* __restrict__ eb,
    const float* __restrict__ eg, const float* __restrict__ ebt,
    const float* __restrict__ sw, const float* __restrict__ sb,
    const float* __restrict__ sg, const float* __restrict__ sbt,
    const float* __restrict__ gateW, const int* __restrict__ gateI,
    float* __restrict__ out)
{
    __shared__ short xs[NROW * ROWB];
    __shared__ float redS[3][8], redQ[3][8];

    const int b = blockIdx.x, g = blockIdx.y;
    const int tid = threadIdx.x;
    const int l = tid & 63, wv = tid >> 6;
    const int n = l & 15, grp = l >> 4;
    const int s_ = grp >> 1, cib = (grp & 1) * 8;

    const int e1 = gateI[b * 2 + 0], e2 = gateI[b * 2 + 1];
    const float scl[3] = {1.0f, gateW[b * 2 + 0], gateW[b * 2 + 1]};

    // ---- stage x[b] -> bf16 transposed
    const float* xb = x + (size_t)b * CIN * T_;
    for (int i = tid; i < CIN * T_; i += NTH) {
        int ci = i >> 11, t = i & 2047;
        xs[(t + 2) * ROWB + ci] = bf16r(xb[i]);
    }
    for (int i = tid; i < 5 * ROWB; i += NTH) {
        int r = i / ROWB, cc = i - r * ROWB;
        int row = (r < 2) ? r : 2048 + r;
        xs[row * ROWB + cc] = 0;
    }

    // ---- A fragments for 3 slots x 3 shift-pairs
    const float* wbase[3] = {
        sw + (size_t)g * CPG * (CIN * KW),
        ew + ((size_t)e1 * 128 + g * CPG) * (CIN * KW),
        ew + ((size_t)e2 * 128 + g * CPG) * (CIN * KW) };
    s16x8 afr[3][3];
    #pragma unroll
    for (int sl = 0; sl < 3; ++sl) {
        #pragma unroll
        for (int p = 0; p < 3; ++p) {
            int sh = 2 * p + s_;
            s16x8 a;
            if (sh < 5) {
                const float* wp = wbase[sl] + (size_t)n * (CIN * KW) + cib * KW + sh;
                #pragma unroll
                for (int j = 0; j < 8; ++j) a[j] = bf16r(wp[j * KW]);
            } else {
                #pragma unroll
                for (int j = 0; j < 8; ++j) a[j] = 0;
            }
            afr[sl][p] = a;
        }
    }
    // per-co params (C/D row co_d = grp*4 + r)
    float bia[3][4], gam[3][4], bet[3][4];
    #pragma unroll
    for (int sl = 0; sl < 3; ++sl) {
        int e = (sl == 1) ? e1 : e2;
        const float* bs = (sl == 0) ? sb  : eb  + e * 128;
        const float* gs = (sl == 0) ? sg  : eg  + e * 128;
        const float* bt = (sl == 0) ? sbt : ebt + e * 128;
        #pragma unroll
        for (int r = 0; r < 4; ++r) {
            int co = g * CPG + grp * 4 + r;
            bia[sl][r] = bs[co]; gam[sl][r] = gs[co]; bet[sl][r] = bt[co];
        }
    }
    __syncthreads();

    // ---- pass 1: conv -> stats only
    float sA[3] = {0.f, 0.f, 0.f}, qA[3] = {0.f, 0.f, 0.f};
    for (int tile = 0; tile < 16; ++tile) {
        const int t0 = (wv * 16 + tile) * 16;
        s16x8 bf0 = *(const s16x8*)&xs[(t0 + n + 0 + s_) * ROWB + cib];
        s16x8 bf1 = *(const s16x8*)&xs[(t0 + n + 2 + s_) * ROWB + cib];
        s16x8 bf2 = *(const s16x8*)&xs[(t0 + n + 4 + s_) * ROWB + cib];
        #pragma unroll
        for (int sl = 0; sl < 3; ++sl) {
            f32x4 c = {0.f, 0.f, 0.f, 0.f};
            c = __builtin_amdgcn_mfma_f32_16x16x32_bf16(afr[sl][0], bf0, c, 0, 0, 0);
            c = __builtin_amdgcn_mfma_f32_16x16x32_bf16(afr[sl][1], bf1, c, 0, 0, 0);
            c = __builtin_amdgcn_mfma_f32_16x16x32_bf16(afr[sl][2], bf2, c, 0, 0, 0);
            #pragma unroll
            for (int r = 0; r < 4; ++r) {
                float v = c[r] + bia[sl][r];
                sA[sl] += v; qA[sl] += v * v;
            }
        }
    }
    #pragma unroll
    for (int sl = 0; sl < 3; ++sl)
        for (int d = 1; d < 64; d <<= 1) {
            sA[sl] += __shfl_xor(sA[sl], d);
            qA[sl] += __shfl_xor(qA[sl], d);
        }
    if (l == 0) {
        #pragma unroll
        for (int sl = 0; sl < 3; ++sl) { redS[sl][wv] = sA[sl]; redQ[sl][wv] = qA[sl]; }
    }
    __syncthreads();
    float mu[3], rs[3];
    const float inv_n = 1.0f / (CPG * T_);
    #pragma unroll
    for (int sl = 0; sl < 3; ++sl) {
        float S = 0.f, Q = 0.f;
        for (int i = 0; i < 8; ++i) { S += redS[sl][i]; Q += redQ[sl][i]; }
        float m = S * inv_n;
        mu[sl] = m;
        rs[sl] = rsqrtf(Q * inv_n - m * m + EPS_);
    }

    // ---- pass 2: recompute conv, normalize+GELU+combine, store
    for (int tile = 0; tile < 16; ++tile) {
        const int t0 = (wv * 16 + tile) * 16;
        s16x8 bf0 = *(const s16x8*)&xs[(t0 + n + 0 + s_) * ROWB + cib];
        s16x8 bf1 = *(const s16x8*)&xs[(t0 + n + 2 + s_) * ROWB + cib];
        s16x8 bf2 = *(const s16x8*)&xs[(t0 + n + 4 + s_) * ROWB + cib];
        f32x4 oacc = {0.f, 0.f, 0.f, 0.f};
        #pragma unroll
        for (int sl = 0; sl < 3; ++sl) {
            f32x4 c = {0.f, 0.f, 0.f, 0.f};
            c = __builtin_amdgcn_mfma_f32_16x16x32_bf16(afr[sl][0], bf0, c, 0, 0, 0);
            c = __builtin_amdgcn_mfma_f32_16x16x32_bf16(afr[sl][1], bf1, c, 0, 0, 0);
            c = __builtin_amdgcn_mfma_f32_16x16x32_bf16(afr[sl][2], bf2, c, 0, 0, 0);
            #pragma unroll
            for (int r = 0; r < 4; ++r) {
                float y = (c[r] + bia[sl][r] - mu[sl]) * rs[sl] * gam[sl][r] + bet[sl][r];
                oacc[r] += scl[sl] * gelu_f(y);
            }
        }
        size_t base = ((size_t)(b * 128 + g * CPG + grp * 4)) * T_ + t0 + n;
        #pragma unroll
        for (int r = 0; r < 4; ++r)
            out[base + (size_t)r * T_] = oacc[r];
    }
}

// ---------------------------------------------------------------------------
extern "C" void kernel_launch(void* const* d_in, const int* in_sizes, int n_in,
                              void* d_out, int out_size, void* d_ws, size_t ws_size,
                              hipStream_t stream)
{
    const float* x    = (const float*)d_in[0];
    const float* demo = (const float*)d_in[1];
    const float* rw   = (const float*)d_in[2];
    const float* rg   = (const float*)d_in[3];
    const float* rb   = (const float*)d_in[4];
    const float* m1w  = (const float*)d_in[5];
    const float* m1b  = (const float*)d_in[6];
    const float* lng  = (const float*)d_in[7];
    const float* lnb  = (const float*)d_in[8];
    const float* m2w  = (const float*)d_in[9];
    const float* m2b  = (const float*)d_in[10];
    const float* d1w  = (const float*)d_in[11];
    const float* d1b  = (const float*)d_in[12];
    const float* dlng = (const float*)d_in[13];
    const float* dlnb = (const float*)d_in[14];
    const float* d2w  = (const float*)d_in[15];
    const float* d2b  = (const float*)d_in[16];
    const float* gw   = (const float*)d_in[17];
    const float* gb   = (const float*)d_in[18];
    const float* ew   = (const float*)d_in[19];
    const float* eb   = (const float*)d_in[20];
    const float* eg   = (const float*)d_in[21];
    const float* ebt  = (const float*)d_in[22];
    const float* sw   = (const float*)d_in[23];
    const float* sb   = (const float*)d_in[24];
    const float* sg   = (const float*)d_in[25];
    const float* sbt  = (const float*)d_in[26];
    float* out = (float*)d_out;

    float* r0    = (float*)d_ws;
    float* gateW = r0 + B_ * HID;
    int*   gateI = (int*)(gateW + 64);

    dim3 gridc(B_, NG);   // b fastest -> all 8 g-blocks of one b share an XCD
    router_conv_kernel<<<gridc, NTH, 0, stream>>>(x, rw, rg, rb, r0);
    router_gate_kernel<<<dim3(B_), 128, 0, stream>>>(
        r0, demo, m1w, m1b, lng, lnb, m2w, m2b,
        d1w, d1b, dlng, dlnb, d2w, d2b, gw, gb, gateW, gateI);
    experts_kernel<<<gridc, NTH, 0, stream>>>(
        x, ew, eb, eg, ebt, sw, sb, sg, sbt, gateW, gateI, out);
    (void)in_sizes; (void)n_in; (void)out_size; (void)ws_size;
}